// Round 4
// baseline (22.640 us; speedup 1.0000x reference)
//
#include <hip/hip_runtime.h>
#include <math.h>

// AntiAliasInterpolation2d: depthwise 13x13 Gaussian (zero-pad 6) on
// (32,3,512,512) fp32 + bilinear x0.25 -> (32,3,128,128).
// Separable: fold the exact 2x2-average downsample into the 13-tap 1D kernel
// -> 14-tap kernel at stride 4, offset -5, vertical then horizontal.
//
// R3: interior-tile specialization (6/8 blocks run a branchless 74-load
// stream -> deeper load clustering), nontemporal output stores (keep L2 for
// input halo reuse). Structure from R2: 512 thr, TI=16, 768 blocks = exactly
// 3 blocks/CU (24 waves/CU), XCD-chunked swizzle, padded LDS (2-way free).

#define H 512
#define W 512
#define OH 128
#define OW 128
#define NC 96
#define TAPS 14
#define TI 16
#define NTILES (OH / TI)            // 8
#define GRID (NC * NTILES)          // 768
#define ROWS (4 * (TI - 1) + TAPS)  // 74
#define LSTRIDE (W + W / 32)        // 528

typedef float f4 __attribute__((ext_vector_type(4)));

struct G14 { float g[TAPS]; };

__global__ __launch_bounds__(512) void aa_interp_kernel(
    const float* __restrict__ x, float* __restrict__ out, G14 gk) {
    // XCD-chunked swizzle: phys %8 = XCD; each XCD gets 96 consecutive
    // logical tiles (12 whole images) so tile halos share that XCD's L2.
    const int bid  = (blockIdx.x & 7) * (GRID / 8) + (blockIdx.x >> 3);
    const int tb   = bid & (NTILES - 1);
    const int nc   = bid >> 3;
    const int t    = threadIdx.x;        // 0..511

    const float* img = x + (size_t)nc * H * W;
    const int r_start = tb * (4 * TI) - 5;

    // ---- Phase 1: vertical 14-tap at stride 4, 16 output rows, 1 col/thread ----
    float acc[TI];
#pragma unroll
    for (int io = 0; io < TI; ++io) acc[io] = 0.f;

    if (tb != 0 && tb != NTILES - 1) {
        // Interior: all 74 rows in range — branchless, loads cluster deep.
        const float* p = img + (size_t)r_start * W + t;
#pragma unroll
        for (int k = 0; k < ROWS; ++k) {
            const float v = p[(size_t)k * W];
            const int lo = (k >= TAPS) ? ((k - TAPS + 4) >> 2) : 0;
            const int hi = ((k >> 2) < (TI - 1)) ? (k >> 2) : (TI - 1);
#pragma unroll
            for (int io = lo; io <= hi; ++io) acc[io] += gk.g[k - 4 * io] * v;
        }
    } else {
        // Edge tiles: predicated loads (zero pad outside [0,H)).
#pragma unroll
        for (int k = 0; k < ROWS; ++k) {
            const int r = r_start + k;
            float v = 0.f;
            if (r >= 0 && r < H) v = img[(size_t)r * W + t];
            const int lo = (k >= TAPS) ? ((k - TAPS + 4) >> 2) : 0;
            const int hi = ((k >> 2) < (TI - 1)) ? (k >> 2) : (TI - 1);
#pragma unroll
            for (int io = lo; io <= hi; ++io) acc[io] += gk.g[k - 4 * io] * v;
        }
    }

    __shared__ float lds[TI * LSTRIDE];
    {
        const int a = t + (t >> 5);      // +1 pad per 32: 2-way aliasing (free)
#pragma unroll
        for (int io = 0; io < TI; ++io) lds[io * LSTRIDE + a] = acc[io];
    }
    __syncthreads();

    // ---- Phase 2: horizontal 14-tap at stride 4; 4 outputs/thread ----
    const int io = t >> 5;               // 0..15 output row in tile
    const int jg = t & 31;               // 32 threads per row
    const int j0 = jg * 4;
    const float* lrow = lds + io * LSTRIDE;
    const int cb = 4 * j0 - 5;

    float win[26];                       // 4*3 + 14
#pragma unroll
    for (int w = 0; w < 26; ++w) {
        const int c = cb + w;
        float v = 0.f;
        if (c >= 0 && c < W) v = lrow[c + (c >> 5)];
        win[w] = v;
    }

    f4 res;
#pragma unroll
    for (int jj = 0; jj < 4; ++jj) {
        float s = 0.f;
#pragma unroll
        for (int v = 0; v < TAPS; ++v) s += gk.g[v] * win[4 * jj + v];
        res[jj] = s;
    }

    float* op = out + ((size_t)nc * OH + tb * TI + io) * OW + j0;
    __builtin_nontemporal_store(res, (f4*)op);  // don't pollute L2/L3
}

extern "C" void kernel_launch(void* const* d_in, const int* in_sizes, int n_in,
                              void* d_out, int out_size, void* d_ws, size_t ws_size,
                              hipStream_t stream) {
    const float* x = (const float*)d_in[0];
    float* out = (float*)d_out;

    // 14-tap fused kernel (13-tap normalized Gaussian, sigma=1.5, convolved
    // with the exact [0.5, 0.5] bilinear-x0.25 average).
    G14 gk;
    {
        double k1[13], s = 0.0;
        for (int d = 0; d < 13; ++d) {
            double dd = d - 6;
            k1[d] = exp(-(dd * dd) / (2.0 * 1.5 * 1.5));
            s += k1[d];
        }
        for (int u = 0; u < TAPS; ++u) {
            double lo = (u - 1 >= 0 && u - 1 < 13) ? k1[u - 1] : 0.0;
            double hi = (u < 13) ? k1[u] : 0.0;
            gk.g[u] = (float)(0.5 * (lo + hi) / s);
        }
    }

    aa_interp_kernel<<<GRID, 512, 0, stream>>>(x, out, gk);
}

// Round 5
// 22.222 us; speedup vs baseline: 1.0188x; 1.0188x over previous
//
#include <hip/hip_runtime.h>
#include <math.h>

// AntiAliasInterpolation2d: depthwise 13x13 Gaussian (zero-pad 6) on
// (32,3,512,512) fp32 + bilinear x0.25 -> (32,3,128,128).
// Separable: fold the exact 2x2-average downsample into the 13-tap 1D kernel
// -> 14-tap kernel at stride 4, offset -5, vertical then horizontal.
//
// R4: revert R3's regressions (edge-specialization, nontemporal stores).
// Keep R2 structure (512 thr, TI=16, 768 blocks = 3/CU, XCD swizzle, padded
// LDS) but load float2/lane via row-parity split: threads 0-255 take even
// rows of each contiguous row-pair, 256-511 odd rows (wave-uniform branch,
// compile-time tap indices on both sides), partials summed in LDS. Halves
// VMEM instruction count at unchanged occupancy/traffic.

#define H 512
#define W 512
#define OH 128
#define OW 128
#define NC 96
#define TAPS 14
#define TI 16
#define NTILES (OH / TI)            // 8
#define GRID (NC * NTILES)          // 768
#define ROWS (4 * (TI - 1) + TAPS)  // 74
#define NPAIRS (ROWS / 2)           // 37
#define LSTRIDE (W + W / 32)        // 528

typedef float f4 __attribute__((ext_vector_type(4)));

struct G14 { float g[TAPS]; };

__global__ __launch_bounds__(512, 6) void aa_interp_kernel(
    const float* __restrict__ x, float* __restrict__ out, G14 gk) {
    // XCD-chunked swizzle: phys %8 = XCD; each XCD gets 96 consecutive
    // logical tiles (12 whole images) so tile halos share that XCD's L2.
    const int bid  = (blockIdx.x & 7) * (GRID / 8) + (blockIdx.x >> 3);
    const int tb   = bid & (NTILES - 1);
    const int nc   = bid >> 3;
    const int t    = threadIdx.x;        // 0..511
    const int half = t >> 8;             // 0: even rows, 1: odd rows
    const int tc   = t & 255;            // column pair index -> cols 2tc,2tc+1

    const float* img  = x + (size_t)nc * H * W;
    const float* colp = img + 2 * tc;
    const int r_start = tb * (4 * TI) - 5;

    // ---- Phase 1: vertical 14-tap at stride 4; 2 cols/thread, own row parity ----
    float acc[TI][2];
#pragma unroll
    for (int io = 0; io < TI; ++io) { acc[io][0] = 0.f; acc[io][1] = 0.f; }

    if (half == 0) {
#pragma unroll
        for (int m = 0; m < NPAIRS; ++m) {
            const int k = 2 * m;                 // compile-time tap base
            const int r = r_start + k;
            float2 v = make_float2(0.f, 0.f);
            if (r >= 0 && r < H) v = *reinterpret_cast<const float2*>(colp + (size_t)r * W);
            const int lo = (k >= TAPS) ? ((k - TAPS + 4) >> 2) : 0;
            const int hi = ((k >> 2) < (TI - 1)) ? (k >> 2) : (TI - 1);
#pragma unroll
            for (int io = lo; io <= hi; ++io) {
                const float g = gk.g[k - 4 * io];
                acc[io][0] += g * v.x;
                acc[io][1] += g * v.y;
            }
        }
    } else {
#pragma unroll
        for (int m = 0; m < NPAIRS; ++m) {
            const int k = 2 * m + 1;             // compile-time tap base
            const int r = r_start + k;
            float2 v = make_float2(0.f, 0.f);
            if (r >= 0 && r < H) v = *reinterpret_cast<const float2*>(colp + (size_t)r * W);
            const int lo = (k >= TAPS) ? ((k - TAPS + 4) >> 2) : 0;
            const int hi = ((k >> 2) < (TI - 1)) ? (k >> 2) : (TI - 1);
#pragma unroll
            for (int io = lo; io <= hi; ++io) {
                const float g = gk.g[k - 4 * io];
                acc[io][0] += g * v.x;
                acc[io][1] += g * v.y;
            }
        }
    }

    // ---- Combine parities in LDS (padded: +1 float per 32 -> conflict-free) ----
    __shared__ float lds[TI * LSTRIDE];
    const int c0 = 2 * tc;
    const int a0 = c0 + (c0 >> 5);   // c0 even => a0, a0+1 always contiguous
    if (half == 1) {
#pragma unroll
        for (int io = 0; io < TI; ++io) {
            lds[io * LSTRIDE + a0]     = acc[io][0];
            lds[io * LSTRIDE + a0 + 1] = acc[io][1];
        }
    }
    __syncthreads();
    if (half == 0) {
#pragma unroll
        for (int io = 0; io < TI; ++io) {
            lds[io * LSTRIDE + a0]     += acc[io][0];
            lds[io * LSTRIDE + a0 + 1] += acc[io][1];
        }
    }
    __syncthreads();

    // ---- Phase 2: horizontal 14-tap at stride 4; 4 outputs/thread ----
    const int io = t >> 5;               // 0..15 output row in tile
    const int jg = t & 31;               // 32 threads per row
    const int j0 = jg * 4;
    const float* lrow = lds + io * LSTRIDE;
    const int cb = 4 * j0 - 5;

    float win[26];                       // 4*3 + 14
#pragma unroll
    for (int w = 0; w < 26; ++w) {
        const int c = cb + w;
        float v = 0.f;
        if (c >= 0 && c < W) v = lrow[c + (c >> 5)];
        win[w] = v;
    }

    f4 res;
#pragma unroll
    for (int jj = 0; jj < 4; ++jj) {
        float s = 0.f;
#pragma unroll
        for (int v = 0; v < TAPS; ++v) s += gk.g[v] * win[4 * jj + v];
        res[jj] = s;
    }

    float* op = out + ((size_t)nc * OH + tb * TI + io) * OW + j0;
    *reinterpret_cast<f4*>(op) = res;
}

extern "C" void kernel_launch(void* const* d_in, const int* in_sizes, int n_in,
                              void* d_out, int out_size, void* d_ws, size_t ws_size,
                              hipStream_t stream) {
    const float* x = (const float*)d_in[0];
    float* out = (float*)d_out;

    // 14-tap fused kernel (13-tap normalized Gaussian, sigma=1.5, convolved
    // with the exact [0.5, 0.5] bilinear-x0.25 average).
    G14 gk;
    {
        double k1[13], s = 0.0;
        for (int d = 0; d < 13; ++d) {
            double dd = d - 6;
            k1[d] = exp(-(dd * dd) / (2.0 * 1.5 * 1.5));
            s += k1[d];
        }
        for (int u = 0; u < TAPS; ++u) {
            double lo = (u - 1 >= 0 && u - 1 < 13) ? k1[u - 1] : 0.0;
            double hi = (u < 13) ? k1[u] : 0.0;
            gk.g[u] = (float)(0.5 * (lo + hi) / s);
        }
    }

    aa_interp_kernel<<<GRID, 512, 0, stream>>>(x, out, gk);
}

// Round 6
// 21.820 us; speedup vs baseline: 1.0376x; 1.0184x over previous
//
#include <hip/hip_runtime.h>
#include <math.h>

// AntiAliasInterpolation2d: depthwise 13x13 Gaussian (zero-pad 6) on
// (32,3,512,512) fp32 + bilinear x0.25 -> (32,3,128,128).
// Separable: fold the exact 2x2-average downsample into the 13-tap 1D kernel
// -> 14-tap kernel at stride 4, offset -5, vertical then horizontal.
//
// R5 = R2 (best measured: 21.9 us, ~90% of achievable HBM BW). R3's
// edge-specialization/nontemporal stores and R4's float2 parity split both
// regressed; reverted. Structure: 512 thr (8 waves -> 24 waves/CU at 3
// blocks/CU, grid 768 = 3x256 exactly), one dword/lane/row coalesced loads,
// XCD-chunked swizzle (halo rows hit same-XCD L2/L3), LDS +1-per-32 pad
// (2-way aliasing = free on CDNA4).

#define H 512
#define W 512
#define OH 128
#define OW 128
#define NC 96
#define TAPS 14
#define TI 16
#define NTILES (OH / TI)            // 8
#define GRID (NC * NTILES)          // 768
#define ROWS (4 * (TI - 1) + TAPS)  // 74
#define LSTRIDE (W + W / 32)        // 528

struct G14 { float g[TAPS]; };

__global__ __launch_bounds__(512) void aa_interp_kernel(
    const float* __restrict__ x, float* __restrict__ out, G14 gk) {
    // XCD-chunked swizzle: phys %8 = XCD; each XCD gets 96 consecutive
    // logical tiles (12 whole images) so tile halos share that XCD's L2.
    const int bid  = (blockIdx.x & 7) * (GRID / 8) + (blockIdx.x >> 3);
    const int tb   = bid & (NTILES - 1);
    const int nc   = bid >> 3;
    const int t    = threadIdx.x;        // 0..511

    const float* img = x + (size_t)nc * H * W;
    const int r_start = tb * (4 * TI) - 5;

    // ---- Phase 1: vertical 14-tap at stride 4, 16 output rows, 1 col/thread ----
    float acc[TI];
#pragma unroll
    for (int io = 0; io < TI; ++io) acc[io] = 0.f;

#pragma unroll
    for (int k = 0; k < ROWS; ++k) {
        const int r = r_start + k;
        float v = 0.f;
        if (r >= 0 && r < H) v = img[(size_t)r * W + t];
        const int lo = (k >= TAPS) ? ((k - TAPS + 4) >> 2) : 0;
        const int hi = ((k >> 2) < (TI - 1)) ? (k >> 2) : (TI - 1);
#pragma unroll
        for (int io = lo; io <= hi; ++io) acc[io] += gk.g[k - 4 * io] * v;
    }

    __shared__ float lds[TI * LSTRIDE];
    {
        const int a = t + (t >> 5);      // +1 pad per 32: 2-way aliasing (free)
#pragma unroll
        for (int io = 0; io < TI; ++io) lds[io * LSTRIDE + a] = acc[io];
    }
    __syncthreads();

    // ---- Phase 2: horizontal 14-tap at stride 4; 4 outputs/thread ----
    const int io = t >> 5;               // 0..15 output row in tile
    const int jg = t & 31;               // 32 threads per row
    const int j0 = jg * 4;
    const float* lrow = lds + io * LSTRIDE;
    const int cb = 4 * j0 - 5;

    float win[26];                       // 4*3 + 14
#pragma unroll
    for (int w = 0; w < 26; ++w) {
        const int c = cb + w;
        float v = 0.f;
        if (c >= 0 && c < W) v = lrow[c + (c >> 5)];
        win[w] = v;
    }

    float res[4];
#pragma unroll
    for (int jj = 0; jj < 4; ++jj) {
        float s = 0.f;
#pragma unroll
        for (int v = 0; v < TAPS; ++v) s += gk.g[v] * win[4 * jj + v];
        res[jj] = s;
    }

    float* op = out + ((size_t)nc * OH + tb * TI + io) * OW + j0;
    reinterpret_cast<float4*>(op)[0] = make_float4(res[0], res[1], res[2], res[3]);
}

extern "C" void kernel_launch(void* const* d_in, const int* in_sizes, int n_in,
                              void* d_out, int out_size, void* d_ws, size_t ws_size,
                              hipStream_t stream) {
    const float* x = (const float*)d_in[0];
    float* out = (float*)d_out;

    // 14-tap fused kernel (13-tap normalized Gaussian, sigma=1.5, convolved
    // with the exact [0.5, 0.5] bilinear-x0.25 average).
    G14 gk;
    {
        double k1[13], s = 0.0;
        for (int d = 0; d < 13; ++d) {
            double dd = d - 6;
            k1[d] = exp(-(dd * dd) / (2.0 * 1.5 * 1.5));
            s += k1[d];
        }
        for (int u = 0; u < TAPS; ++u) {
            double lo = (u - 1 >= 0 && u - 1 < 13) ? k1[u - 1] : 0.0;
            double hi = (u < 13) ? k1[u] : 0.0;
            gk.g[u] = (float)(0.5 * (lo + hi) / s);
        }
    }

    aa_interp_kernel<<<GRID, 512, 0, stream>>>(x, out, gk);
}